// Round 1
// baseline (236.706 us; speedup 1.0000x reference)
//
#include <hip/hip_runtime.h>

typedef __attribute__((ext_vector_type(8))) short bf16x8;
typedef __attribute__((ext_vector_type(4))) short bf16x4;
typedef __attribute__((ext_vector_type(4))) float f32x4;

#define NB 128
#define LL 512
#define HH 128
#define HDIM 64
#define NROWS (NB * LL)  // 65536

__device__ __forceinline__ unsigned short f2b(float f) {
  unsigned int x = __float_as_uint(f);
  x = (x + 0x7fffu + ((x >> 16) & 1u)) >> 16;  // RNE
  return (unsigned short)x;
}

__device__ __forceinline__ bf16x8 load8_cvt(const float* p) {
  float4 a = *(const float4*)p;
  float4 b = *(const float4*)(p + 4);
  bf16x8 r;
  r[0] = (short)f2b(a.x); r[1] = (short)f2b(a.y);
  r[2] = (short)f2b(a.z); r[3] = (short)f2b(a.w);
  r[4] = (short)f2b(b.x); r[5] = (short)f2b(b.y);
  r[6] = (short)f2b(b.z); r[7] = (short)f2b(b.w);
  return r;
}

#if __has_builtin(__builtin_amdgcn_mfma_f32_16x16x16bf16_1k)
__device__ __forceinline__ f32x4 mfma16(bf16x4 a, bf16x4 b, f32x4 c) {
  return __builtin_amdgcn_mfma_f32_16x16x16bf16_1k(a, b, c, 0, 0, 0);
}
#else
__device__ __forceinline__ f32x4 mfma16(bf16x4 a, bf16x4 b, f32x4 c) {
  asm volatile("s_nop 1\n\t"
               "v_mfma_f32_16x16x16_bf16 %0, %1, %2, %0\n\t"
               "s_nop 7\n\t"
               "s_nop 7"
               : "+v"(c) : "v"(a), "v"(b));
  return c;
}
#endif

// ---------------------------------------------------------------------------
// Projection kernel: computes (bf16 outputs)
//   Qo  [65536][128] = queries @ Qw^T + Qb
//   Ko  [65536][128] = keys @ Kw^T + Kb + nbr + nat + pk
//   Vt  [2][128][64][512] (transposed) = keys @ Vw^T + Vb + nbr + nat + pv
// Block: 256 threads (4 waves), 64 rows per block, full 128 cols.
// ---------------------------------------------------------------------------
__global__ __launch_bounds__(256) void proj_kernel(
    const float* __restrict__ queries, const float* __restrict__ keys,
    const float* __restrict__ nbr, const float* __restrict__ nat,
    const float* __restrict__ pk, const float* __restrict__ pv,
    const float* __restrict__ Qw, const float* __restrict__ Qbias,
    const float* __restrict__ Kw, const float* __restrict__ Kbias,
    const float* __restrict__ Vw, const float* __restrict__ Vbias,
    unsigned short* __restrict__ Qo, unsigned short* __restrict__ Ko,
    unsigned short* __restrict__ Vt) {
  __shared__ unsigned short wlds[128 * 136];  // W as bf16, padded stride 136

  const int tid = threadIdx.x;
  const int lane = tid & 63;
  const int wave = tid >> 6;
  const int g = lane >> 4;    // 0..3
  const int qi = lane & 15;   // 0..15
  const long rowbase = (long)blockIdx.x * 64 + wave * 16;
  const long arow = rowbase + qi;

  // A fragments: lane holds row (l&15), k = 8*(l>>4)+j within each k-tile of 32
  bf16x8 aq[4], ak[4];
#pragma unroll
  for (int kt = 0; kt < 4; ++kt) {
    const int kk = kt * 32 + g * 8;
    aq[kt] = load8_cvt(queries + arow * 128 + kk);
    ak[kt] = load8_cvt(keys + arow * 128 + kk);
  }

  float tmp[8][4];  // nbr+nat cached between K and V epilogues

  const float* Ws[3] = {Qw, Kw, Vw};
  const float* Bs[3] = {Qbias, Kbias, Vbias};

#pragma unroll
  for (int p = 0; p < 3; ++p) {
    if (p) __syncthreads();
    // cooperative load of W (fp32 -> bf16) into LDS
    const float* W = Ws[p];
#pragma unroll
    for (int i = 0; i < 16; ++i) {
      int f4 = tid + 256 * i;  // 0..4095 float4s
      int row = f4 >> 5;
      int c4 = f4 & 31;
      float4 v = *(const float4*)(W + row * 128 + c4 * 4);
      ushort4 u;
      u.x = f2b(v.x); u.y = f2b(v.y); u.z = f2b(v.z); u.w = f2b(v.w);
      *(ushort4*)&wlds[row * 136 + c4 * 4] = u;
    }
    __syncthreads();

    // GEMM: acc[ct] covers cols [ct*16, ct*16+16)
    f32x4 acc[8];
#pragma unroll
    for (int ct = 0; ct < 8; ++ct) {
      acc[ct] = f32x4{0.f, 0.f, 0.f, 0.f};
#pragma unroll
      for (int kt = 0; kt < 4; ++kt) {
        bf16x8 af = (p == 0) ? aq[kt] : ak[kt];
        bf16x8 bf = *(const bf16x8*)&wlds[(ct * 16 + qi) * 136 + kt * 32 + g * 8];
        acc[ct] = __builtin_amdgcn_mfma_f32_16x16x32_bf16(af, bf, acc[ct], 0, 0, 0);
      }
    }

    // Epilogue. C layout: col = ct*16 + (l&15), row = rowbase + 4*(l>>4) + reg
#pragma unroll
    for (int ct = 0; ct < 8; ++ct) {
      const int c = ct * 16 + qi;
      const float bias = Bs[p][c];
#pragma unroll
      for (int reg = 0; reg < 4; ++reg) {
        const long r = rowbase + 4 * g + reg;
        if (p == 0) {
          Qo[r * 128 + c] = f2b(acc[ct][reg] + bias);
        } else if (p == 1) {
          const float add = nbr[r * 128 + c] + nat[r * 128 + c];
          tmp[ct][reg] = add;
          Ko[r * 128 + c] = f2b(acc[ct][reg] + bias + add + pk[r * 128 + c]);
        } else {
          const float val = acc[ct][reg] + bias + tmp[ct][reg] + pv[r * 128 + c];
          const int hh = c >> 6, d = c & 63;
          const long bidx = r >> 9, lrow = r & 511;
          Vt[(((long)hh * NB + bidx) * HDIM + d) * LL + lrow] = f2b(val);
        }
      }
    }
  }
}

// ---------------------------------------------------------------------------
// Attention kernel: flash-style, swapped QK^T so P lands in the 16x16x16
// A-fragment layout with zero shuffles.
// Grid: (8 q-tiles, 128 batch, 2 heads), 256 threads = 4 waves x 16 q-rows.
// ---------------------------------------------------------------------------
__global__ __launch_bounds__(256) void attn_kernel(
    const unsigned short* __restrict__ Qb, const unsigned short* __restrict__ Kb,
    const unsigned short* __restrict__ Vt, float* __restrict__ out) {
  const int qt = blockIdx.x;
  const int b = blockIdx.y;
  const int h = blockIdx.z;
  const int tid = threadIdx.x;
  const int lane = tid & 63;
  const int wave = tid >> 6;
  const int g = lane >> 4;
  const int qi = lane & 15;
  const int qbase = qt * 64 + wave * 16;
  const int myq = qbase + qi;

  // Q fragments (B operand of swapped QK^T): col q = l&15, k = d contiguous
  const unsigned short* Qrow = Qb + ((long)(b * LL + qbase + qi)) * HH + h * HDIM;
  const bf16x8 qf0 = *(const bf16x8*)(Qrow + g * 8);
  const bf16x8 qf1 = *(const bf16x8*)(Qrow + 32 + g * 8);

  f32x4 o[4];
#pragma unroll
  for (int dt = 0; dt < 4; ++dt) o[dt] = f32x4{0.f, 0.f, 0.f, 0.f};
  float m = -1e30f, lsum = 0.f;

  const int kmax = qt * 64 + 64;
  const unsigned short* Vbase = Vt + ((long)(h * NB + b)) * HDIM * LL;

  for (int k0 = 0; k0 < kmax; k0 += 16) {
    // Ksum A fragment: row = key k0 + (l&15), k = d contiguous
    const unsigned short* Krow = Kb + ((long)(b * LL + k0 + qi)) * HH + h * HDIM;
    const bf16x8 kf0 = *(const bf16x8*)(Krow + g * 8);
    const bf16x8 kf1 = *(const bf16x8*)(Krow + 32 + g * 8);

    f32x4 s = f32x4{0.f, 0.f, 0.f, 0.f};
    s = __builtin_amdgcn_mfma_f32_16x16x32_bf16(kf0, qf0, s, 0, 0, 0);
    s = __builtin_amdgcn_mfma_f32_16x16x32_bf16(kf1, qf1, s, 0, 0, 0);
    // S' layout: lane holds q = l&15 (col), keys k0 + 4g + reg (rows)

    float p[4];
    float pm = -1e30f;
#pragma unroll
    for (int r2 = 0; r2 < 4; ++r2) {
      float sv = s[r2] * 0.125f;          // 1/sqrt(64)
      const int key = k0 + 4 * g + r2;
      sv = (key > myq) ? -1e30f : sv;     // causal mask
      p[r2] = sv;
      pm = fmaxf(pm, sv);
    }
    // row-max across the 4 lane-groups holding this q
    pm = fmaxf(pm, __shfl_xor(pm, 16));
    pm = fmaxf(pm, __shfl_xor(pm, 32));
    const float mnew = fmaxf(m, pm);
    const float alpha = exp2f((m - mnew) * 1.44269504f);
    float ps = 0.f;
#pragma unroll
    for (int r2 = 0; r2 < 4; ++r2) {
      p[r2] = exp2f((p[r2] - mnew) * 1.44269504f);
      ps += p[r2];
    }
    ps += __shfl_xor(ps, 16);
    ps += __shfl_xor(ps, 32);
    lsum = lsum * alpha + ps;
    m = mnew;

    // P fragment for PV (A of 16x16x16): row q = l&15, k = 4g+reg -- direct!
    bf16x4 pf;
    pf[0] = (short)f2b(p[0]); pf[1] = (short)f2b(p[1]);
    pf[2] = (short)f2b(p[2]); pf[3] = (short)f2b(p[3]);

    // alpha per O-row (O rows are q = 4g+reg): transpose via shfl
    const float a0 = __shfl(alpha, 4 * g + 0);
    const float a1 = __shfl(alpha, 4 * g + 1);
    const float a2 = __shfl(alpha, 4 * g + 2);
    const float a3 = __shfl(alpha, 4 * g + 3);
#pragma unroll
    for (int dt = 0; dt < 4; ++dt) {
      o[dt][0] *= a0; o[dt][1] *= a1; o[dt][2] *= a2; o[dt][3] *= a3;
      const bf16x4 vf = *(const bf16x4*)(Vbase + (dt * 16 + qi) * LL + k0 + 4 * g);
      o[dt] = mfma16(pf, vf, o[dt]);
    }
  }

  // epilogue: divide by row sums (transpose lsum to O-row layout)
  float linv[4];
#pragma unroll
  for (int reg = 0; reg < 4; ++reg) linv[reg] = 1.0f / __shfl(lsum, 4 * g + reg);
#pragma unroll
  for (int dt = 0; dt < 4; ++dt) {
#pragma unroll
    for (int reg = 0; reg < 4; ++reg) {
      const long r = (long)(b * LL + qbase + 4 * g + reg);
      out[r * HH + h * HDIM + dt * 16 + qi] = o[dt][reg] * linv[reg];
    }
  }
}

extern "C" void kernel_launch(void* const* d_in, const int* in_sizes, int n_in,
                              void* d_out, int out_size, void* d_ws, size_t ws_size,
                              hipStream_t stream) {
  const float* queries = (const float*)d_in[0];
  const float* keys    = (const float*)d_in[1];
  const float* nbr     = (const float*)d_in[2];
  const float* nat     = (const float*)d_in[3];
  const float* pk      = (const float*)d_in[4];
  const float* pv      = (const float*)d_in[5];
  const float* Qw      = (const float*)d_in[6];
  const float* Qbias   = (const float*)d_in[7];
  const float* Kw      = (const float*)d_in[8];
  const float* Kbias   = (const float*)d_in[9];
  const float* Vw      = (const float*)d_in[10];
  const float* Vbias   = (const float*)d_in[11];
  // d_in[12] = attn_mask: exact causal ~tril, computed analytically in-kernel.

  unsigned short* Qo = (unsigned short*)d_ws;
  unsigned short* Ko = Qo + (size_t)NROWS * HH;
  unsigned short* Vt = Ko + (size_t)NROWS * HH;

  proj_kernel<<<NROWS / 64, 256, 0, stream>>>(queries, keys, nbr, nat, pk, pv,
                                              Qw, Qbias, Kw, Kbias, Vw, Vbias,
                                              Qo, Ko, Vt);

  dim3 grid(LL / 64, NB, 2);
  attn_kernel<<<grid, 256, 0, stream>>>(Qo, Ko, Vt, (float*)d_out);
}

// Round 2
// 154.844 us; speedup vs baseline: 1.5287x; 1.5287x over previous
//
#include <hip/hip_runtime.h>

typedef __attribute__((ext_vector_type(8))) short bf16x8;
typedef __attribute__((ext_vector_type(4))) short bf16x4;
typedef __attribute__((ext_vector_type(4))) float f32x4;

#define NB 128
#define LL 512
#define HH 128
#define HDIM 64
#define NROWS (NB * LL)  // 65536

__device__ __forceinline__ unsigned short f2b(float f) {
  unsigned int x = __float_as_uint(f);
  x = (x + 0x7fffu + ((x >> 16) & 1u)) >> 16;  // RNE
  return (unsigned short)x;
}

__device__ __forceinline__ bf16x8 load8_cvt(const float* p) {
  float4 a = *(const float4*)p;
  float4 b = *(const float4*)(p + 4);
  bf16x8 r;
  r[0] = (short)f2b(a.x); r[1] = (short)f2b(a.y);
  r[2] = (short)f2b(a.z); r[3] = (short)f2b(a.w);
  r[4] = (short)f2b(b.x); r[5] = (short)f2b(b.y);
  r[6] = (short)f2b(b.z); r[7] = (short)f2b(b.w);
  return r;
}

#if __has_builtin(__builtin_amdgcn_mfma_f32_16x16x16bf16_1k)
__device__ __forceinline__ f32x4 mfma16(bf16x4 a, bf16x4 b, f32x4 c) {
  return __builtin_amdgcn_mfma_f32_16x16x16bf16_1k(a, b, c, 0, 0, 0);
}
#else
__device__ __forceinline__ f32x4 mfma16(bf16x4 a, bf16x4 b, f32x4 c) {
  asm volatile("s_nop 1\n\t"
               "v_mfma_f32_16x16x16_bf16 %0, %1, %2, %0\n\t"
               "s_nop 7\n\t"
               "s_nop 7"
               : "+v"(c) : "v"(a), "v"(b));
  return c;
}
#endif

__device__ __forceinline__ f32x4 mfma32(bf16x8 a, bf16x8 b, f32x4 c) {
  return __builtin_amdgcn_mfma_f32_16x16x32_bf16(a, b, c, 0, 0, 0);
}

// ---------------------------------------------------------------------------
// Projection kernel (unchanged from R0): bf16 outputs
//   Qo  [65536][128] = queries @ Qw^T + Qb
//   Ko  [65536][128] = keys @ Kw^T + Kb + nbr + nat + pk
//   Vt  [2][128][64][512] (transposed) = keys @ Vw^T + Vb + nbr + nat + pv
// ---------------------------------------------------------------------------
__global__ __launch_bounds__(256) void proj_kernel(
    const float* __restrict__ queries, const float* __restrict__ keys,
    const float* __restrict__ nbr, const float* __restrict__ nat,
    const float* __restrict__ pk, const float* __restrict__ pv,
    const float* __restrict__ Qw, const float* __restrict__ Qbias,
    const float* __restrict__ Kw, const float* __restrict__ Kbias,
    const float* __restrict__ Vw, const float* __restrict__ Vbias,
    unsigned short* __restrict__ Qo, unsigned short* __restrict__ Ko,
    unsigned short* __restrict__ Vt) {
  __shared__ unsigned short wlds[128 * 136];

  const int tid = threadIdx.x;
  const int lane = tid & 63;
  const int wave = tid >> 6;
  const int g = lane >> 4;
  const int qi = lane & 15;
  const long rowbase = (long)blockIdx.x * 64 + wave * 16;
  const long arow = rowbase + qi;

  bf16x8 aq[4], ak[4];
#pragma unroll
  for (int kt = 0; kt < 4; ++kt) {
    const int kk = kt * 32 + g * 8;
    aq[kt] = load8_cvt(queries + arow * 128 + kk);
    ak[kt] = load8_cvt(keys + arow * 128 + kk);
  }

  float tmp[8][4];

  const float* Ws[3] = {Qw, Kw, Vw};
  const float* Bs[3] = {Qbias, Kbias, Vbias};

#pragma unroll
  for (int p = 0; p < 3; ++p) {
    if (p) __syncthreads();
    const float* W = Ws[p];
#pragma unroll
    for (int i = 0; i < 16; ++i) {
      int f4 = tid + 256 * i;
      int row = f4 >> 5;
      int c4 = f4 & 31;
      float4 v = *(const float4*)(W + row * 128 + c4 * 4);
      ushort4 u;
      u.x = f2b(v.x); u.y = f2b(v.y); u.z = f2b(v.z); u.w = f2b(v.w);
      *(ushort4*)&wlds[row * 136 + c4 * 4] = u;
    }
    __syncthreads();

    f32x4 acc[8];
#pragma unroll
    for (int ct = 0; ct < 8; ++ct) {
      acc[ct] = f32x4{0.f, 0.f, 0.f, 0.f};
#pragma unroll
      for (int kt = 0; kt < 4; ++kt) {
        bf16x8 af = (p == 0) ? aq[kt] : ak[kt];
        bf16x8 bf = *(const bf16x8*)&wlds[(ct * 16 + qi) * 136 + kt * 32 + g * 8];
        acc[ct] = mfma32(af, bf, acc[ct]);
      }
    }

#pragma unroll
    for (int ct = 0; ct < 8; ++ct) {
      const int c = ct * 16 + qi;
      const float bias = Bs[p][c];
#pragma unroll
      for (int reg = 0; reg < 4; ++reg) {
        const long r = rowbase + 4 * g + reg;
        if (p == 0) {
          Qo[r * 128 + c] = f2b(acc[ct][reg] + bias);
        } else if (p == 1) {
          const float add = nbr[r * 128 + c] + nat[r * 128 + c];
          tmp[ct][reg] = add;
          Ko[r * 128 + c] = f2b(acc[ct][reg] + bias + add + pk[r * 128 + c]);
        } else {
          const float val = acc[ct][reg] + bias + tmp[ct][reg] + pv[r * 128 + c];
          const int hh = c >> 6, d = c & 63;
          const long bidx = r >> 9, lrow = r & 511;
          Vt[(((long)hh * NB + bidx) * HDIM + d) * LL + lrow] = f2b(val);
        }
      }
    }
  }
}

// ---------------------------------------------------------------------------
// Attention kernel v2: K-tile = 64 keys/iteration, 32 q-rows per wave
// (two 16-q fragments sharing K and V fragments). Swapped QK^T so P lands
// directly in the 16x16x16 A-fragment layout (zero shuffles for P).
// Grid: (4 q-tiles of 128, 128 batch, 2 heads), 256 threads = 4 waves.
// ---------------------------------------------------------------------------
__global__ __launch_bounds__(256) void attn_kernel(
    const unsigned short* __restrict__ Qb, const unsigned short* __restrict__ Kb,
    const unsigned short* __restrict__ Vt, float* __restrict__ out) {
  const int qt = blockIdx.x;
  const int b = blockIdx.y;
  const int h = blockIdx.z;
  const int tid = threadIdx.x;
  const int lane = tid & 63;
  const int wave = tid >> 6;
  const int g = lane >> 4;
  const int qi = lane & 15;
  const int qbase = qt * 128 + wave * 32;

  // Q fragments (B operand of swapped QK^T): col q = l&15, k = d
  bf16x8 qf[2][2];
#pragma unroll
  for (int q2 = 0; q2 < 2; ++q2) {
    const unsigned short* Qrow =
        Qb + ((long)(b * LL + qbase + q2 * 16 + qi)) * HH + h * HDIM;
    qf[q2][0] = *(const bf16x8*)(Qrow + g * 8);
    qf[q2][1] = *(const bf16x8*)(Qrow + 32 + g * 8);
  }

  f32x4 o[2][4];
#pragma unroll
  for (int q2 = 0; q2 < 2; ++q2)
#pragma unroll
    for (int dt = 0; dt < 4; ++dt) o[q2][dt] = f32x4{0.f, 0.f, 0.f, 0.f};
  float m[2] = {-1e30f, -1e30f};
  float lsum[2] = {0.f, 0.f};

  const int ntile = (qbase >> 6) + 1;  // causal: tiles fully above diag skipped
  const unsigned short* Vbase = Vt + ((long)(h * NB + b)) * HDIM * LL;

  for (int it = 0; it < ntile; ++it) {
    const int k0 = it * 64;

    // K fragments for 64 keys: row = key (l&15 within 16-tile), k = d
    bf16x8 kf[4][2];
#pragma unroll
    for (int t = 0; t < 4; ++t) {
      const unsigned short* Krow =
          Kb + ((long)(b * LL + k0 + t * 16 + qi)) * HH + h * HDIM;
      kf[t][0] = *(const bf16x8*)(Krow + g * 8);
      kf[t][1] = *(const bf16x8*)(Krow + 32 + g * 8);
    }

    // S' = (K+...)Q^T : lane holds q = l&15 (col), key rows t*16 + 4g + reg
    f32x4 s[2][4];
#pragma unroll
    for (int q2 = 0; q2 < 2; ++q2)
#pragma unroll
      for (int t = 0; t < 4; ++t) {
        f32x4 acc = f32x4{0.f, 0.f, 0.f, 0.f};
        acc = mfma32(kf[t][0], qf[q2][0], acc);
        acc = mfma32(kf[t][1], qf[q2][1], acc);
        s[q2][t] = acc;
      }

    float alpha[2];
    bf16x4 pf[2][4];
#pragma unroll
    for (int q2 = 0; q2 < 2; ++q2) {
      const int myq = qbase + q2 * 16 + qi;
      float p[16];
      float pm = -1e30f;
#pragma unroll
      for (int t = 0; t < 4; ++t)
#pragma unroll
        for (int r = 0; r < 4; ++r) {
          float sv = s[q2][t][r] * 0.125f;       // 1/sqrt(64)
          const int key = k0 + t * 16 + 4 * g + r;
          sv = (key > myq) ? -1e30f : sv;        // causal mask
          p[t * 4 + r] = sv;
          pm = fmaxf(pm, sv);
        }
      pm = fmaxf(pm, __shfl_xor(pm, 16));
      pm = fmaxf(pm, __shfl_xor(pm, 32));
      const float mnew = fmaxf(m[q2], pm);
      alpha[q2] = exp2f((m[q2] - mnew) * 1.44269504f);
      float ps = 0.f;
#pragma unroll
      for (int i = 0; i < 16; ++i) {
        p[i] = exp2f((p[i] - mnew) * 1.44269504f);
        ps += p[i];
      }
      ps += __shfl_xor(ps, 16);
      ps += __shfl_xor(ps, 32);
      lsum[q2] = lsum[q2] * alpha[q2] + ps;
      m[q2] = mnew;
#pragma unroll
      for (int t = 0; t < 4; ++t) {
        pf[q2][t][0] = (short)f2b(p[t * 4 + 0]);
        pf[q2][t][1] = (short)f2b(p[t * 4 + 1]);
        pf[q2][t][2] = (short)f2b(p[t * 4 + 2]);
        pf[q2][t][3] = (short)f2b(p[t * 4 + 3]);
      }
    }

    // O-rescale factors transposed to O-row layout (rows q = 4g+reg)
    float ar[2][4];
#pragma unroll
    for (int q2 = 0; q2 < 2; ++q2)
#pragma unroll
      for (int r = 0; r < 4; ++r) ar[q2][r] = __shfl(alpha[q2], 4 * g + r);

#pragma unroll
    for (int dt = 0; dt < 4; ++dt) {
#pragma unroll
      for (int q2 = 0; q2 < 2; ++q2) {
        o[q2][dt][0] *= ar[q2][0];
        o[q2][dt][1] *= ar[q2][1];
        o[q2][dt][2] *= ar[q2][2];
        o[q2][dt][3] *= ar[q2][3];
      }
#pragma unroll
      for (int t = 0; t < 4; ++t) {
        const bf16x4 vf =
            *(const bf16x4*)(Vbase + (dt * 16 + qi) * LL + k0 + t * 16 + 4 * g);
        o[0][dt] = mfma16(pf[0][t], vf, o[0][dt]);
        o[1][dt] = mfma16(pf[1][t], vf, o[1][dt]);
      }
    }
  }

  // epilogue: divide by row sums (transposed to O-row layout)
#pragma unroll
  for (int q2 = 0; q2 < 2; ++q2) {
    float linv[4];
#pragma unroll
    for (int r = 0; r < 4; ++r) linv[r] = 1.0f / __shfl(lsum[q2], 4 * g + r);
#pragma unroll
    for (int dt = 0; dt < 4; ++dt)
#pragma unroll
      for (int r = 0; r < 4; ++r) {
        const long row = (long)(b * LL + qbase + q2 * 16 + 4 * g + r);
        out[row * HH + h * HDIM + dt * 16 + qi] = o[q2][dt][r] * linv[r];
      }
  }
}

extern "C" void kernel_launch(void* const* d_in, const int* in_sizes, int n_in,
                              void* d_out, int out_size, void* d_ws, size_t ws_size,
                              hipStream_t stream) {
  const float* queries = (const float*)d_in[0];
  const float* keys    = (const float*)d_in[1];
  const float* nbr     = (const float*)d_in[2];
  const float* nat     = (const float*)d_in[3];
  const float* pk      = (const float*)d_in[4];
  const float* pv      = (const float*)d_in[5];
  const float* Qw      = (const float*)d_in[6];
  const float* Qbias   = (const float*)d_in[7];
  const float* Kw      = (const float*)d_in[8];
  const float* Kbias   = (const float*)d_in[9];
  const float* Vw      = (const float*)d_in[10];
  const float* Vbias   = (const float*)d_in[11];
  // d_in[12] = attn_mask: exact causal ~tril, computed analytically in-kernel.

  unsigned short* Qo = (unsigned short*)d_ws;
  unsigned short* Ko = Qo + (size_t)NROWS * HH;
  unsigned short* Vt = Ko + (size_t)NROWS * HH;

  proj_kernel<<<NROWS / 64, 256, 0, stream>>>(queries, keys, nbr, nat, pk, pv,
                                              Qw, Qbias, Kw, Kbias, Vw, Vbias,
                                              Qo, Ko, Vt);

  dim3 grid(LL / 128, NB, 2);
  attn_kernel<<<grid, 256, 0, stream>>>(Qo, Ko, Vt, (float*)d_out);
}